// Round 5
// baseline (426.119 us; speedup 1.0000x reference)
//
#include <hip/hip_runtime.h>
#include <math.h>
#include <stdint.h>

#define H 2048
#define B 1024
#define NB 12
#define NSTEP 23

#define NBLK 256
#define NTHR 512

#define NEMB 176      // 166 used (44 act + 121 block + zero), padded
#define ZSLOT 165

// ---------------- ws layout (bytes) ----------------
// Ex: E pre-swizzled into MFMA A-fragment order:
//   v8s slot [(m*64 + ks)*64 + quad*16 + l16] = E[m*16+l16][ks*32+quad*8 .. +7]
#define OFF_E    0ull
#define SZ_E     ((size_t)NEMB * H * 2ull)             // 704 KB bf16
#define OFF_H0   (OFF_E + SZ_E)                        // u64[2048] tagged h, buf0
#define OFF_H1   (OFF_H0 + 16384ull)                   // u64[2048] tagged h, buf1
#define OFF_CB   (OFF_H1 + 16384ull)                   // u64[2048] tagged c
#define WS_NEED  (OFF_CB + 16384ull)

typedef __attribute__((ext_vector_type(8))) short v8s;
typedef __attribute__((ext_vector_type(4))) float v4f;

__device__ __forceinline__ uint32_t bf16rne(float f) {
    uint32_t u = __float_as_uint(f);
    return (u + 0x7fffu + ((u >> 16) & 1u)) >> 16;
}
__device__ __forceinline__ float sigm(float x) { return 1.f / (1.f + expf(-x)); }

// 8-byte atomic {value, epoch} store to the agent coherence point
__device__ __forceinline__ void st_tag(unsigned long long* p, float v, int tag) {
    unsigned long long u = (unsigned long long)__float_as_uint(v) |
                           ((unsigned long long)(unsigned)tag << 32);
    __hip_atomic_store(p, u, __ATOMIC_RELAXED, __HIP_MEMORY_SCOPE_AGENT);
}

// fused barrier + allgather: spin on 4 tagged pairs (32 B) until epoch arrives
__device__ __forceinline__ float4 poll_gather(const unsigned long long* buf,
                                              int tid, int e) {
    int4 a, b;
    const int* p = (const int*)(buf + (size_t)tid * 4);
    long guard = 0;
    for (;;) {
        asm volatile("global_load_dwordx4 %0, %2, off sc0 sc1\n\t"
                     "global_load_dwordx4 %1, %3, off sc0 sc1\n\t"
                     "s_waitcnt vmcnt(0)"
                     : "=&v"(a), "=&v"(b)
                     : "v"(p), "v"(p + 4)
                     : "memory");
        if (a.y >= e && a.w >= e && b.y >= e && b.w >= e) break;
        if (++guard > (1L << 26)) break;  // failsafe: never hard-hang
        __builtin_amdgcn_s_sleep(1);
    }
    float4 r;
    r.x = __int_as_float(a.x); r.y = __int_as_float(a.z);
    r.z = __int_as_float(b.x); r.w = __int_as_float(b.z);
    return r;
}

// ------- gather embeddings -> bf16 Ex (A-frag order); block 176 zeros tags
__global__ __launch_bounds__(256) void build_e_kernel(
    const float* __restrict__ enc_act, const float* __restrict__ enc_block,
    uint32_t* __restrict__ Ex, uint4* __restrict__ tags) {
    const int r = blockIdx.x;
    const int t = threadIdx.x;
    if (r == NEMB) {   // zero 48 KB of tag buffers (hb0, hb1, cb)
        const uint4 z = {0, 0, 0, 0};
#pragma unroll
        for (int i = 0; i < 12; ++i) tags[i * 256 + t] = z;
        return;
    }
    uint4 o = {0, 0, 0, 0};
    const float* src = nullptr;
    if (r < 44) src = enc_act + (size_t)r * H;
    else if (r < 165) src = enc_block + (size_t)(r - 44) * H;
    if (src) {
        float4 a = ((const float4*)src)[2 * t];
        float4 b = ((const float4*)src)[2 * t + 1];
        o.x = bf16rne(a.x) | (bf16rne(a.y) << 16);
        o.y = bf16rne(a.z) | (bf16rne(a.w) << 16);
        o.z = bf16rne(b.x) | (bf16rne(b.y) << 16);
        o.w = bf16rne(b.z) | (bf16rne(b.w) << 16);
    }
    // thread t holds E[r][8t .. 8t+7] -> Ex fragment slot
    const int m = r >> 4, l16 = r & 15;
    const int ks = t >> 2, quad = t & 3;
    ((uint4*)Ex)[(size_t)(m * 64 + ks) * 64 + quad * 16 + l16] = o;
}

// ---------------- persistent LSTM (prologue: quant W_hh + MFMA PRE) ------
__device__ __forceinline__ float cvt_lo16(uint32_t u) {
    return (float)((int)(u << 16) >> 16);
}
__device__ __forceinline__ float cvt_hi16(uint32_t u) {
    return (float)((int)u >> 16);
}
__device__ __forceinline__ float i16dot(uint4 w, float4 a, float4 b) {
    return cvt_lo16(w.x) * a.x + cvt_hi16(w.x) * a.y +
           cvt_lo16(w.y) * a.z + cvt_hi16(w.y) * a.w +
           cvt_lo16(w.z) * b.x + cvt_hi16(w.z) * b.y +
           cvt_lo16(w.w) * b.z + cvt_hi16(w.w) * b.w;
}
__device__ __forceinline__ uint32_t pack16(int lo, int hi) {
    return ((uint32_t)lo & 0xffffu) | ((uint32_t)hi << 16);
}

__global__ __launch_bounds__(NTHR, 1) void lstm_persist(
    const float* __restrict__ Wih,
    const float* __restrict__ Whh,
    const float* __restrict__ bih, const float* __restrict__ bhh,
    const uint16_t* __restrict__ Ex,
    const float* __restrict__ dec_act, const float* __restrict__ dec_block,
    unsigned long long* __restrict__ hb0,
    unsigned long long* __restrict__ hb1,
    unsigned long long* __restrict__ cb,
    float* __restrict__ out) {
    __shared__ uint4 Wl[32 * 256];     // 128 KB  int16 W_hh slice
    __shared__ float h_s[H];           // 8 KB
    __shared__ float pre_s[NEMB * 32]; // 22 KB   all embs x this block's cols
    __shared__ float logits_s[16];     // total 161856 B <= 163840

    const int tid = threadIdx.x;
    const int w = tid >> 6;
    const int lane = tid & 63;
    const int bid = blockIdx.x;

    // ---- prologue A: quantize this block's 32 gate-rows of W_hh into LDS.
    // Arithmetic identical to original quant kernel: per-row absmax (full
    // row held by one wave), scale = max/32767.
    float sc[4];
#pragma unroll
    for (int g = 0; g < 4; ++g) {
        const float4* w4 =
            (const float4*)(Whh + ((size_t)g * H + bid * 8 + w) * H);
        float4 f[8];
        float m = 0.f;
#pragma unroll
        for (int k = 0; k < 8; ++k) {
            f[k] = w4[lane * 8 + k];
            m = fmaxf(m, fmaxf(fmaxf(fabsf(f[k].x), fabsf(f[k].y)),
                               fmaxf(fabsf(f[k].z), fabsf(f[k].w))));
        }
#pragma unroll
        for (int off = 32; off > 0; off >>= 1)
            m = fmaxf(m, __shfl_xor(m, off, 64));
        const float inv = (m > 0.f) ? 32767.f / m : 0.f;
        sc[g] = (m > 0.f) ? m / 32767.f : 0.f;
#pragma unroll
        for (int k = 0; k < 4; ++k) {
            int q0 = (int)rintf(f[2 * k].x * inv);
            int q1 = (int)rintf(f[2 * k].y * inv);
            int q2 = (int)rintf(f[2 * k].z * inv);
            int q3 = (int)rintf(f[2 * k].w * inv);
            int q4 = (int)rintf(f[2 * k + 1].x * inv);
            int q5 = (int)rintf(f[2 * k + 1].y * inv);
            int q6 = (int)rintf(f[2 * k + 1].z * inv);
            int q7 = (int)rintf(f[2 * k + 1].w * inv);
            uint4 o;
            o.x = pack16(q0, q1); o.y = pack16(q2, q3);
            o.z = pack16(q4, q5); o.w = pack16(q6, q7);
            Wl[(g * 8 + w) * 256 + lane * 4 + k] = o;
        }
    }

    // ---- prologue B: pre_s[emb][c] = (E @ Wih^T)[emb][col(c)] + bias,
    // c = g*8+ow over this block's 32 output columns. MFMA 16x16x32:
    // A = Ex fragments (M=emb), B = Wih rows (N=cols). Wave w: N-tile
    // n=w>>2, M-tiles m = (w&3)+4i.
    {
        const int n = w >> 2;
        const int msel = w & 3;
        const int l16 = lane & 15;
        const int quad = lane >> 4;
        const int c = n * 16 + l16;                       // 0..31
        const int gr = (c >> 3) * H + bid * 8 + (c & 7);  // Wih/bias row
        const float bb = bih[gr] + bhh[gr];
        const float* wp = Wih + (size_t)gr * H;
        const int nm = (msel == 3) ? 2 : 3;

        v4f acc[3];
#pragma unroll
        for (int i = 0; i < 3; ++i) acc[i] = (v4f){0.f, 0.f, 0.f, 0.f};

        for (int ks = 0; ks < 64; ++ks) {
            const int ko = ks * 32 + quad * 8;
            float4 wa = *(const float4*)(wp + ko);
            float4 wb = *(const float4*)(wp + ko + 4);
            v8s bfrag;
            bfrag[0] = (short)bf16rne(wa.x); bfrag[1] = (short)bf16rne(wa.y);
            bfrag[2] = (short)bf16rne(wa.z); bfrag[3] = (short)bf16rne(wa.w);
            bfrag[4] = (short)bf16rne(wb.x); bfrag[5] = (short)bf16rne(wb.y);
            bfrag[6] = (short)bf16rne(wb.z); bfrag[7] = (short)bf16rne(wb.w);
#pragma unroll
            for (int i = 0; i < 3; ++i) {
                if (i < nm) {
                    const int m = msel + 4 * i;
                    v8s afrag = *(const v8s*)(Ex +
                        ((size_t)(m * 64 + ks) * 64 + lane) * 8);
                    acc[i] = __builtin_amdgcn_mfma_f32_16x16x32_bf16(
                        afrag, bfrag, acc[i], 0, 0, 0);
                }
            }
        }
#pragma unroll
        for (int i = 0; i < 3; ++i) {
            if (i < nm) {
                const int m = msel + 4 * i;
#pragma unroll
                for (int r = 0; r < 4; ++r) {
                    const int emb = m * 16 + quad * 4 + r;
                    pre_s[emb * 32 + c] = acc[i][r] + bb;
                }
            }
        }
    }

    for (int j = tid; j < H; j += NTHR) h_s[j] = 0.f;
    float c_reg = 0.f;
    int emb = ZSLOT;
    int idx = 0;
    __syncthreads();

    for (int t = 0; t < NSTEP; ++t) {
        unsigned long long* hb = (t & 1) ? hb1 : hb0;
        const int e = t + 1;

        float prev = 0.f;
        if (lane < 4) prev = pre_s[emb * 32 + lane * 8 + w];

        float acc[4] = {0.f, 0.f, 0.f, 0.f};
#pragma unroll
        for (int cc = 0; cc < 4; ++cc) {
            const int ci = cc * 64 + lane;
            const float4 ha = ((const float4*)h_s)[2 * ci];
            const float4 hv2 = ((const float4*)h_s)[2 * ci + 1];
#pragma unroll
            for (int g = 0; g < 4; ++g) {
                uint4 wv4 = Wl[(g * 8 + w) * 256 + ci];
                acc[g] += i16dot(wv4, ha, hv2);
            }
        }
#pragma unroll
        for (int off = 32; off > 0; off >>= 1)
#pragma unroll
            for (int g = 0; g < 4; ++g)
                acc[g] += __shfl_xor(acc[g], off, 64);

        float gv[4];
#pragma unroll
        for (int g = 0; g < 4; ++g)
            gv[g] = acc[g] * sc[g] + __shfl(prev, g, 64);

        float cn = sigm(gv[1]) * c_reg + sigm(gv[0]) * tanhf(gv[2]);
        float hn = sigm(gv[3]) * tanhf(cn);
        c_reg = cn;
        // one atomic 8-B store: {h value, epoch}. Data-dependent on all of
        // this wave's h_s reads -> tag visibility implies reads retired.
        if (lane == 0) st_tag(hb + bid * 8 + w, hn, e);

        // fused grid-barrier + h allgather (single coherent round-trip)
        float4 hv = poll_gather(hb, tid, e);
        ((float4*)h_s)[tid] = hv;
        __syncthreads();

        // decoder logits computed redundantly per block from L2-cached
        // weights (<= 11 x 2048 MACs)
        int nclass; const float* dec;
        if (t == 0) { nclass = 4; dec = dec_act; }
        else if (t & 1) {
            int b2 = (t + 1) >> 1; nclass = b2;
            dec = dec_block + (size_t)(b2 - 1) * (NB - 1) * H;
        } else {
            int b2 = t >> 1; nclass = 4;
            dec = dec_act + (size_t)b2 * 4 * H;
        }
        for (int cl = w; cl < nclass; cl += 8) {
            const float4* dr = (const float4*)(dec + (size_t)cl * H);
            float s = 0.f;
#pragma unroll
            for (int k = 0; k < 8; ++k) {
                int j = k * 64 + lane;
                float4 dv = dr[j];
                float4 hh = ((const float4*)h_s)[j];
                s += dv.x * hh.x + dv.y * hh.y + dv.z * hh.z + dv.w * hh.w;
            }
#pragma unroll
            for (int off = 32; off > 0; off >>= 1)
                s += __shfl_xor(s, off, 64);
            if (lane == 0) logits_s[cl] = s;
        }
        __syncthreads();
        {
            float best = logits_s[0]; int bi = 0;
            for (int cl = 1; cl < nclass; ++cl)
                if (logits_s[cl] > best) { best = logits_s[cl]; bi = cl; }
            idx = bi;
        }
        if (t < NSTEP - 1) {
            if ((t & 1) == 0) emb = (t >> 1) * 4 + idx;
            else emb = 44 + ((t - 1) >> 1) * 11 + idx;
        }
        // no trailing barrier: a wave can only overwrite h_s/logits_s at t+1
        // after every wave here stored its tagged h(t+1), which is
        // data-dependent on that wave having finished reading h_s(t)
    }

    // final c exchange via the same tagged poll
    if (lane == 0) st_tag(cb + bid * 8 + w, c_reg, 1);
    float4 cv4 = poll_gather(cb, tid, 1);

    if (bid == 0) { out[tid] = (float)idx; out[tid + NTHR] = (float)idx; }
    float4 hv4 = ((const float4*)h_s)[tid];
    float4* oh = (float4*)(out + B);
    float4* oc = (float4*)(out + B + (size_t)B * H);
#pragma unroll
    for (int r = 0; r < 4; ++r) {
        int orow = bid * 4 + r;
        oh[(size_t)orow * (H / 4) + tid] = hv4;
        oc[(size_t)orow * (H / 4) + tid] = cv4;
    }
}

// ---------------- fp32 fallback path (tiny ws) — R1-proven ---------------
__global__ __launch_bounds__(256) void zero_c_kernel(float* __restrict__ cv) {
    int j = blockIdx.x * 256 + threadIdx.x;
    if (j < H) cv[j] = 0.f;
}
__global__ __launch_bounds__(256) void bias_gates_kernel(
    const float* __restrict__ bih, const float* __restrict__ bhh,
    float* __restrict__ gates) {
    int j = blockIdx.x * 256 + threadIdx.x;
    if (j < 4 * H) gates[j] = bih[j] + bhh[j];
}
__global__ __launch_bounds__(256) void gates_kernel(
    const float* __restrict__ Wih, const float* __restrict__ Whh,
    const float* __restrict__ bih, const float* __restrict__ bhh,
    const float* __restrict__ x, const float* __restrict__ h,
    float* __restrict__ gates) {
    const int wave = threadIdx.x >> 6;
    const int lane = threadIdx.x & 63;
    const int row = blockIdx.x * 4 + wave;
    const float4* Wi4 = (const float4*)(Wih + (size_t)row * H);
    const float4* Wh4 = (const float4*)(Whh + (size_t)row * H);
    const float4* x4 = (const float4*)x;
    const float4* h4 = (const float4*)h;
    float acc = 0.f;
#pragma unroll
    for (int k = 0; k < H / 256; ++k) {
        int j = k * 64 + lane;
        float4 wv = Wi4[j]; float4 v = x4[j];
        acc += wv.x * v.x + wv.y * v.y + wv.z * v.z + wv.w * v.w;
    }
#pragma unroll
    for (int k = 0; k < H / 256; ++k) {
        int j = k * 64 + lane;
        float4 wv = Wh4[j]; float4 v = h4[j];
        acc += wv.x * v.x + wv.y * v.y + wv.z * v.z + wv.w * v.w;
    }
    for (int off = 32; off > 0; off >>= 1) acc += __shfl_down(acc, off, 64);
    if (lane == 0) gates[row] = acc + bih[row] + bhh[row];
}
__global__ __launch_bounds__(256) void update_kernel(
    const float* __restrict__ gates,
    float* __restrict__ xv, float* __restrict__ hv, float* __restrict__ cv,
    const float* __restrict__ dec, int nclass,
    const float* __restrict__ enc, int* __restrict__ idx_ptr) {
    const int t = threadIdx.x;
    __shared__ float red[256];
    __shared__ float logits[16];
    __shared__ int sidx;
    float hl[8];
#pragma unroll
    for (int k = 0; k < 8; ++k) {
        int j = k * 256 + t;
        float si = sigm(gates[j]);
        float sf = sigm(gates[H + j]);
        float so = sigm(gates[3 * H + j]);
        float tg = tanhf(gates[2 * H + j]);
        float c2 = sf * cv[j] + si * tg;
        float h2 = so * tanhf(c2);
        cv[j] = c2; hv[j] = h2; hl[k] = h2;
    }
    __syncthreads();
    for (int cl = 0; cl < nclass; ++cl) {
        const float* dr = dec + (size_t)cl * H;
        float p = 0.f;
#pragma unroll
        for (int k = 0; k < 8; ++k) p += hl[k] * dr[k * 256 + t];
        red[t] = p;
        __syncthreads();
        for (int s = 128; s > 0; s >>= 1) {
            if (t < s) red[t] += red[t + s];
            __syncthreads();
        }
        if (t == 0) logits[cl] = red[0];
        __syncthreads();
    }
    if (t == 0) {
        float best = logits[0]; int bi = 0;
        for (int cl = 1; cl < nclass; ++cl)
            if (logits[cl] > best) { best = logits[cl]; bi = cl; }
        sidx = bi; *idx_ptr = bi;
    }
    __syncthreads();
    if (enc != nullptr) {
        const float* er = enc + (size_t)sidx * H;
#pragma unroll
        for (int k = 0; k < 8; ++k) xv[k * 256 + t] = er[k * 256 + t];
    }
}
__global__ __launch_bounds__(256) void final_kernel(
    const float* __restrict__ hv, const float* __restrict__ cv,
    const int* __restrict__ idx_ptr, float* __restrict__ out) {
    const int tid = blockIdx.x * 256 + threadIdx.x;
    const int col = tid & (H / 4 - 1);
    ((float4*)(out + B))[tid] = ((const float4*)hv)[col];
    ((float4*)(out + B + (size_t)B * H))[tid] = ((const float4*)cv)[col];
    if (tid < B) out[tid] = (float)(*idx_ptr);
}

extern "C" void kernel_launch(void* const* d_in, const int* in_sizes, int n_in,
                              void* d_out, int out_size, void* d_ws, size_t ws_size,
                              hipStream_t stream) {
    const float* W_ih      = (const float*)d_in[1];
    const float* W_hh      = (const float*)d_in[2];
    const float* b_ih      = (const float*)d_in[3];
    const float* b_hh      = (const float*)d_in[4];
    const float* enc_act   = (const float*)d_in[5];
    const float* enc_block = (const float*)d_in[6];
    const float* dec_act   = (const float*)d_in[7];
    const float* dec_block = (const float*)d_in[8];
    float* out = (float*)d_out;
    char* ws = (char*)d_ws;

    if (ws_size >= WS_NEED) {
        uint32_t* Ex = (uint32_t*)(ws + OFF_E);
        unsigned long long* hb0 = (unsigned long long*)(ws + OFF_H0);
        unsigned long long* hb1 = (unsigned long long*)(ws + OFF_H1);
        unsigned long long* cbf = (unsigned long long*)(ws + OFF_CB);

        build_e_kernel<<<NEMB + 1, 256, 0, stream>>>(
            enc_act, enc_block, Ex, (uint4*)(ws + OFF_H0));
        lstm_persist<<<NBLK, NTHR, 0, stream>>>(
            W_ih, W_hh, b_ih, b_hh, (const uint16_t*)Ex,
            dec_act, dec_block, hb0, hb1, cbf, out);
        return;
    }

    // fallback: fp32 multi-kernel path
    float* state = (float*)d_ws;
    float* xv = state;
    float* hv = state + H;
    float* cv = state + 2 * H;
    float* gates = state + 3 * H;
    int* idxp = (int*)(state + 7 * H);

    zero_c_kernel<<<8, 256, 0, stream>>>(cv);
    bias_gates_kernel<<<32, 256, 0, stream>>>(b_ih, b_hh, gates);
    update_kernel<<<1, 256, 0, stream>>>(gates, xv, hv, cv, dec_act, 4,
                                         enc_act, idxp);
    for (int bid = 1; bid < NB; ++bid) {
        gates_kernel<<<2048, 256, 0, stream>>>(W_ih, W_hh, b_ih, b_hh,
                                               xv, hv, gates);
        update_kernel<<<1, 256, 0, stream>>>(
            gates, xv, hv, cv,
            dec_block + (size_t)(bid - 1) * (NB - 1) * H, bid,
            enc_block + (size_t)(bid - 1) * (NB - 1) * H, idxp);
        gates_kernel<<<2048, 256, 0, stream>>>(W_ih, W_hh, b_ih, b_hh,
                                               xv, hv, gates);
        update_kernel<<<1, 256, 0, stream>>>(
            gates, xv, hv, cv,
            dec_act + (size_t)bid * 4 * H, 4,
            (bid < NB - 1) ? (enc_act + (size_t)bid * 4 * H) : nullptr, idxp);
    }
    final_kernel<<<2048, 256, 0, stream>>>(hv, cv, idxp, out);
}

// Round 6
// 412.023 us; speedup vs baseline: 1.0342x; 1.0342x over previous
//
#include <hip/hip_runtime.h>
#include <math.h>
#include <stdint.h>

#define H 2048
#define B 1024
#define NB 12
#define NSTEP 23

#define NBLK 256
#define NTHR 512

#define NEMB 176      // 166 used (44 act + 121 block + zero), padded
#define ZSLOT 165

// ---------------- ws layout (bytes) ----------------
// Ex: E pre-swizzled into MFMA A-fragment order:
//   v8s slot [(m*64 + ks)*64 + quad*16 + l16] = E[m*16+l16][ks*32+quad*8 .. +7]
// Wx: W_ih pre-swizzled into MFMA B-fragment order per (bid,n) tile:
//   v8s slot [ti*4096 + ks*64 + lane] = bf16 W_ih[grow(ti,lane)][ks*32+quad*8 ..]
#define OFF_E    0ull
#define SZ_E     ((size_t)NEMB * H * 2ull)             // 704 KB bf16
#define OFF_WX   (OFF_E + SZ_E)
#define SZ_WX    (512ull * 4096ull * 16ull)            // 32 MB bf16
#define OFF_H0   (OFF_WX + SZ_WX)                      // u64[2048] tagged h, buf0
#define OFF_H1   (OFF_H0 + 16384ull)                   // u64[2048] tagged h, buf1
#define OFF_CB   (OFF_H1 + 16384ull)                   // u64[2048] tagged c
#define WS_NEED  (OFF_CB + 16384ull)

typedef __attribute__((ext_vector_type(8))) short v8s;
typedef __attribute__((ext_vector_type(4))) float v4f;

__device__ __forceinline__ uint32_t bf16rne(float f) {
    uint32_t u = __float_as_uint(f);
    return (u + 0x7fffu + ((u >> 16) & 1u)) >> 16;
}
__device__ __forceinline__ float sigm(float x) { return 1.f / (1.f + expf(-x)); }

// 8-byte atomic {value, epoch} store to the agent coherence point
__device__ __forceinline__ void st_tag(unsigned long long* p, float v, int tag) {
    unsigned long long u = (unsigned long long)__float_as_uint(v) |
                           ((unsigned long long)(unsigned)tag << 32);
    __hip_atomic_store(p, u, __ATOMIC_RELAXED, __HIP_MEMORY_SCOPE_AGENT);
}
__device__ __forceinline__ int4 ld_agent_i4(const int* p) {
    int4 r;
    asm volatile("global_load_dwordx4 %0, %1, off sc0 sc1\n\t"
                 "s_waitcnt vmcnt(0)"
                 : "=v"(r) : "v"(p) : "memory");
    return r;
}

// fused barrier + allgather with done-mask: thread polls its OWN 4 pairs
// (= h[4*tid .. 4*tid+3]); once a 16-B half is valid it is never re-read.
__device__ __forceinline__ float4 poll4(const unsigned long long* buf,
                                        int tid, int e) {
    const int* pa = (const int*)(buf + (size_t)tid * 4);
    const int* pb = pa + 4;
    int4 a, b;
    asm volatile("global_load_dwordx4 %0, %2, off sc0 sc1\n\t"
                 "global_load_dwordx4 %1, %3, off sc0 sc1\n\t"
                 "s_waitcnt vmcnt(0)"
                 : "=&v"(a), "=&v"(b)
                 : "v"(pa), "v"(pb) : "memory");
    bool da = (a.y >= e) && (a.w >= e);
    bool db = (b.y >= e) && (b.w >= e);
    long guard = 0;
    while (!(da && db)) {
        if (++guard > (1L << 24)) break;  // failsafe: never hard-hang
        __builtin_amdgcn_s_sleep(1);
        if (!da) { a = ld_agent_i4(pa); da = (a.y >= e) && (a.w >= e); }
        if (!db) { b = ld_agent_i4(pb); db = (b.y >= e) && (b.w >= e); }
    }
    float4 r;
    r.x = __int_as_float(a.x); r.y = __int_as_float(a.z);
    r.z = __int_as_float(b.x); r.w = __int_as_float(b.z);
    return r;
}

// ------- gather embeddings -> bf16 Ex (A-frag order); block 176 zeros tags
__global__ __launch_bounds__(256) void build_e_kernel(
    const float* __restrict__ enc_act, const float* __restrict__ enc_block,
    uint32_t* __restrict__ Ex, uint4* __restrict__ tags) {
    const int r = blockIdx.x;
    const int t = threadIdx.x;
    if (r == NEMB) {   // zero 48 KB of tag buffers (hb0, hb1, cb)
        const uint4 z = {0, 0, 0, 0};
#pragma unroll
        for (int i = 0; i < 12; ++i) tags[i * 256 + t] = z;
        return;
    }
    uint4 o = {0, 0, 0, 0};
    const float* src = nullptr;
    if (r < 44) src = enc_act + (size_t)r * H;
    else if (r < 165) src = enc_block + (size_t)(r - 44) * H;
    if (src) {
        float4 a = ((const float4*)src)[2 * t];
        float4 b = ((const float4*)src)[2 * t + 1];
        o.x = bf16rne(a.x) | (bf16rne(a.y) << 16);
        o.y = bf16rne(a.z) | (bf16rne(a.w) << 16);
        o.z = bf16rne(b.x) | (bf16rne(b.y) << 16);
        o.w = bf16rne(b.z) | (bf16rne(b.w) << 16);
    }
    // thread t holds E[r][8t .. 8t+7] -> Ex fragment slot
    const int m = r >> 4, l16 = r & 15;
    const int ks = t >> 2, quad = t & 3;
    ((uint4*)Ex)[(size_t)(m * 64 + ks) * 64 + quad * 16 + l16] = o;
}

// ------- W_ih -> bf16 Wx (B-fragment order per (bid,n) tile) -------------
// ti = bid*2+n. Slot lane: quad=lane>>4, l16=lane&15; c = n*16+l16;
// grow = (c>>3)*H + bid*8 + (c&7). Coalesced 1 KB wave-writes.
__global__ __launch_bounds__(256) void wx_kernel(
    const float* __restrict__ Wih, uint32_t* __restrict__ Wx) {
    const int ti = blockIdx.x;            // 0..511
    const int bidb = ti >> 1, n = ti & 1;
    const int t = threadIdx.x;
#pragma unroll
    for (int i = 0; i < 16; ++i) {
        const int slot = i * 256 + t;     // = ks*64 + lane
        const int ks = slot >> 6;
        const int lane = slot & 63;
        const int quad = lane >> 4, l16 = lane & 15;
        const int grow = (2 * n + (l16 >> 3)) * H + bidb * 8 + (l16 & 7);
        const float* src = Wih + (size_t)grow * H + ks * 32 + quad * 8;
        float4 wa = *(const float4*)src;
        float4 wb = *(const float4*)(src + 4);
        uint4 o;
        o.x = bf16rne(wa.x) | (bf16rne(wa.y) << 16);
        o.y = bf16rne(wa.z) | (bf16rne(wa.w) << 16);
        o.z = bf16rne(wb.x) | (bf16rne(wb.y) << 16);
        o.w = bf16rne(wb.z) | (bf16rne(wb.w) << 16);
        ((uint4*)Wx)[(size_t)ti * 4096 + slot] = o;
    }
}

// ---------------- persistent LSTM ----------------------------------------
__device__ __forceinline__ float cvt_lo16(uint32_t u) {
    return (float)((int)(u << 16) >> 16);
}
__device__ __forceinline__ float cvt_hi16(uint32_t u) {
    return (float)((int)u >> 16);
}
__device__ __forceinline__ float i16dot(uint4 w, float4 a, float4 b) {
    return cvt_lo16(w.x) * a.x + cvt_hi16(w.x) * a.y +
           cvt_lo16(w.y) * a.z + cvt_hi16(w.y) * a.w +
           cvt_lo16(w.z) * b.x + cvt_hi16(w.z) * b.y +
           cvt_lo16(w.w) * b.z + cvt_hi16(w.w) * b.w;
}
__device__ __forceinline__ uint32_t pack16(int lo, int hi) {
    return ((uint32_t)lo & 0xffffu) | ((uint32_t)hi << 16);
}

__global__ __launch_bounds__(NTHR, 1) void lstm_persist(
    const uint16_t* __restrict__ Wx,
    const float* __restrict__ Whh,
    const float* __restrict__ bih, const float* __restrict__ bhh,
    const uint16_t* __restrict__ Ex,
    const float* __restrict__ dec_act, const float* __restrict__ dec_block,
    unsigned long long* __restrict__ hb0,
    unsigned long long* __restrict__ hb1,
    unsigned long long* __restrict__ cb,
    float* __restrict__ out) {
    __shared__ uint4 Wl[32 * 256];     // 128 KB  int16 W_hh slice
    __shared__ float h_s[H];           // 8 KB
    __shared__ float pre_s[NEMB * 32]; // 22 KB   all embs x this block's cols
    __shared__ float lpart_s[128];     // 8 waves x 16 logit partials

    const int tid = threadIdx.x;
    const int w = tid >> 6;
    const int lane = tid & 63;
    const int bid = blockIdx.x;
    const int vmap4 = ((lane & 1) << 3) | ((lane & 2) << 1) |
                      ((lane & 4) >> 1) | ((lane & 8) >> 3);

    // ---- prologue A: quantize this block's 32 gate-rows of W_hh into LDS.
    // Arithmetic identical to original quant kernel.
    float sc[4];
#pragma unroll
    for (int g = 0; g < 4; ++g) {
        const float4* w4 =
            (const float4*)(Whh + ((size_t)g * H + bid * 8 + w) * H);
        float4 f[8];
        float m = 0.f;
#pragma unroll
        for (int k = 0; k < 8; ++k) {
            f[k] = w4[lane * 8 + k];
            m = fmaxf(m, fmaxf(fmaxf(fabsf(f[k].x), fabsf(f[k].y)),
                               fmaxf(fabsf(f[k].z), fabsf(f[k].w))));
        }
#pragma unroll
        for (int off = 32; off > 0; off >>= 1)
            m = fmaxf(m, __shfl_xor(m, off, 64));
        const float inv = (m > 0.f) ? 32767.f / m : 0.f;
        sc[g] = (m > 0.f) ? m / 32767.f : 0.f;
#pragma unroll
        for (int k = 0; k < 4; ++k) {
            int q0 = (int)rintf(f[2 * k].x * inv);
            int q1 = (int)rintf(f[2 * k].y * inv);
            int q2 = (int)rintf(f[2 * k].z * inv);
            int q3 = (int)rintf(f[2 * k].w * inv);
            int q4 = (int)rintf(f[2 * k + 1].x * inv);
            int q5 = (int)rintf(f[2 * k + 1].y * inv);
            int q6 = (int)rintf(f[2 * k + 1].z * inv);
            int q7 = (int)rintf(f[2 * k + 1].w * inv);
            uint4 o;
            o.x = pack16(q0, q1); o.y = pack16(q2, q3);
            o.z = pack16(q4, q5); o.w = pack16(q6, q7);
            Wl[(g * 8 + w) * 256 + lane * 4 + k] = o;
        }
    }

    // ---- prologue B: pre_s[emb][c] = (E @ Wih^T)[emb][col(c)] + bias.
    // All-coalesced: A-frags from Ex, B-frags from Wx (both pre-swizzled).
    {
        const int n = w >> 2;
        const int msel = w & 3;
        const int l16 = lane & 15;
        const int quad = lane >> 4;
        const int c = n * 16 + l16;                       // 0..31
        const int gr = (c >> 3) * H + bid * 8 + (c & 7);  // bias row
        const float bb = bih[gr] + bhh[gr];
        const int nm = (msel == 3) ? 2 : 3;
        const uint16_t* wxt = Wx + (size_t)(bid * 2 + n) * 32768;

        v4f acc[3];
#pragma unroll
        for (int i = 0; i < 3; ++i) acc[i] = (v4f){0.f, 0.f, 0.f, 0.f};

        for (int ks = 0; ks < 64; ++ks) {
            v8s bfrag = *(const v8s*)(wxt + ((size_t)(ks * 64) + lane) * 8);
#pragma unroll
            for (int i = 0; i < 3; ++i) {
                if (i < nm) {
                    const int m = msel + 4 * i;
                    v8s afrag = *(const v8s*)(Ex +
                        ((size_t)(m * 64 + ks) * 64 + lane) * 8);
                    acc[i] = __builtin_amdgcn_mfma_f32_16x16x32_bf16(
                        afrag, bfrag, acc[i], 0, 0, 0);
                }
            }
        }
#pragma unroll
        for (int i = 0; i < 3; ++i) {
            if (i < nm) {
                const int m = msel + 4 * i;
#pragma unroll
                for (int r = 0; r < 4; ++r) {
                    const int emb = m * 16 + quad * 4 + r;
                    pre_s[emb * 32 + c] = acc[i][r] + bb;
                }
            }
        }
    }

    for (int j = tid; j < H; j += NTHR) h_s[j] = 0.f;
    float c_reg = 0.f;
    int emb = ZSLOT;
    int idx = 0;
    __syncthreads();

    for (int t = 0; t < NSTEP; ++t) {
        unsigned long long* hb = (t & 1) ? hb1 : hb0;
        const int e = t + 1;

        // decoder for THIS step depends only on t -> prefetch rows into
        // registers now; L2 latency hides under gemv + poll wait.
        int nclass; const float* dec;
        if (t == 0) { nclass = 4; dec = dec_act; }
        else if (t & 1) {
            int b2 = (t + 1) >> 1; nclass = b2;
            dec = dec_block + (size_t)(b2 - 1) * (NB - 1) * H;
        } else {
            int b2 = t >> 1; nclass = 4;
            dec = dec_act + (size_t)b2 * 4 * H;
        }
        const float4* dec4 = (const float4*)dec;
        float4 dpre[11];
#pragma unroll
        for (int cl = 0; cl < 11; ++cl)
            if (cl < nclass) dpre[cl] = dec4[(size_t)cl * 512 + tid];

        float prev = 0.f;
        if (lane < 4) prev = pre_s[emb * 32 + lane * 8 + w];

        float acc[4] = {0.f, 0.f, 0.f, 0.f};
#pragma unroll
        for (int cc = 0; cc < 4; ++cc) {
            const int ci = cc * 64 + lane;
            const float4 ha = ((const float4*)h_s)[2 * ci];
            const float4 hv2 = ((const float4*)h_s)[2 * ci + 1];
#pragma unroll
            for (int g = 0; g < 4; ++g) {
                uint4 wv4 = Wl[(g * 8 + w) * 256 + ci];
                acc[g] += i16dot(wv4, ha, hv2);
            }
        }
#pragma unroll
        for (int off = 32; off > 0; off >>= 1)
#pragma unroll
            for (int g = 0; g < 4; ++g)
                acc[g] += __shfl_xor(acc[g], off, 64);

        float gv[4];
#pragma unroll
        for (int g = 0; g < 4; ++g)
            gv[g] = acc[g] * sc[g] + __shfl(prev, g, 64);

        float cn = sigm(gv[1]) * c_reg + sigm(gv[0]) * tanhf(gv[2]);
        float hn = sigm(gv[3]) * tanhf(cn);
        c_reg = cn;
        // one atomic 8-B store: {h value, epoch}. Data-dependent on all of
        // this wave's h_s reads -> tag visibility implies reads retired.
        if (lane == 0) st_tag(hb + bid * 8 + w, hn, e);

        // fused grid-barrier + allgather of exactly this thread's h columns
        float4 h4 = poll4(hb, tid, e);
        ((float4*)h_s)[tid] = h4;

        // logits from own h4 (prefetched dec rows) -- no h_s dependency
        float lp[16];
#pragma unroll
        for (int cl = 0; cl < 16; ++cl) lp[cl] = 0.f;
#pragma unroll
        for (int cl = 0; cl < 11; ++cl)
            if (cl < nclass)
                lp[cl] = dpre[cl].x * h4.x + dpre[cl].y * h4.y +
                         dpre[cl].z * h4.z + dpre[cl].w * h4.w;
        {
            const bool bit = (lane & 1) != 0;
#pragma unroll
            for (int i = 0; i < 8; ++i) {
                float x = lp[i], y = lp[i + 8];
                float mine = bit ? y : x, oth = bit ? x : y;
                lp[i] = mine + __shfl_xor(oth, 1, 64);
            }
        }
        {
            const bool bit = (lane & 2) != 0;
#pragma unroll
            for (int i = 0; i < 4; ++i) {
                float x = lp[i], y = lp[i + 4];
                float mine = bit ? y : x, oth = bit ? x : y;
                lp[i] = mine + __shfl_xor(oth, 2, 64);
            }
        }
        {
            const bool bit = (lane & 4) != 0;
#pragma unroll
            for (int i = 0; i < 2; ++i) {
                float x = lp[i], y = lp[i + 2];
                float mine = bit ? y : x, oth = bit ? x : y;
                lp[i] = mine + __shfl_xor(oth, 4, 64);
            }
        }
        {
            const bool bit = (lane & 8) != 0;
            float x = lp[0], y = lp[1];
            float mine = bit ? y : x, oth = bit ? x : y;
            lp[0] = mine + __shfl_xor(oth, 8, 64);
        }
        lp[0] += __shfl_xor(lp[0], 16, 64);
        lp[0] += __shfl_xor(lp[0], 32, 64);
        if (lane < 16) lpart_s[w * 16 + vmap4] = lp[0];
        __syncthreads();   // single barrier per step: h_s + lpart_s ready
        {
            const int cl = lane & 15;
            float s = 0.f;
#pragma unroll
            for (int w2 = 0; w2 < 8; ++w2) s += lpart_s[w2 * 16 + cl];
            float av = (cl < nclass) ? s : -3.0e38f;
            int ac = cl;
#pragma unroll
            for (int m = 1; m <= 8; m <<= 1) {
                float ov = __shfl_xor(av, m, 64);
                int oc = __shfl_xor(ac, m, 64);
                if (ov > av || (ov == av && oc < ac)) { av = ov; ac = oc; }
            }
            idx = ac;   // identical on every thread of every block
        }
        if (t < NSTEP - 1) {
            if ((t & 1) == 0) emb = (t >> 1) * 4 + idx;
            else emb = 44 + ((t - 1) >> 1) * 11 + idx;
        }
        // no trailing barrier: a wave's next h_s/lpart_s write requires its
        // poll(t+2 tags) which requires every wave's gemv(t+1) h_s reads
    }

    // final c exchange via the same tagged poll
    if (lane == 0) st_tag(cb + bid * 8 + w, c_reg, 1);
    float4 cv4 = poll4(cb, tid, 1);

    if (bid == 0) { out[tid] = (float)idx; out[tid + NTHR] = (float)idx; }
    float4 hv4 = ((const float4*)h_s)[tid];   // own write, no sync needed
    float4* oh = (float4*)(out + B);
    float4* oc = (float4*)(out + B + (size_t)B * H);
#pragma unroll
    for (int r = 0; r < 4; ++r) {
        int orow = bid * 4 + r;
        oh[(size_t)orow * (H / 4) + tid] = hv4;
        oc[(size_t)orow * (H / 4) + tid] = cv4;
    }
}

// ---------------- fp32 fallback path (tiny ws) — R1-proven ---------------
__global__ __launch_bounds__(256) void zero_c_kernel(float* __restrict__ cv) {
    int j = blockIdx.x * 256 + threadIdx.x;
    if (j < H) cv[j] = 0.f;
}
__global__ __launch_bounds__(256) void bias_gates_kernel(
    const float* __restrict__ bih, const float* __restrict__ bhh,
    float* __restrict__ gates) {
    int j = blockIdx.x * 256 + threadIdx.x;
    if (j < 4 * H) gates[j] = bih[j] + bhh[j];
}
__global__ __launch_bounds__(256) void gates_kernel(
    const float* __restrict__ Wih, const float* __restrict__ Whh,
    const float* __restrict__ bih, const float* __restrict__ bhh,
    const float* __restrict__ x, const float* __restrict__ h,
    float* __restrict__ gates) {
    const int wave = threadIdx.x >> 6;
    const int lane = threadIdx.x & 63;
    const int row = blockIdx.x * 4 + wave;
    const float4* Wi4 = (const float4*)(Wih + (size_t)row * H);
    const float4* Wh4 = (const float4*)(Whh + (size_t)row * H);
    const float4* x4 = (const float4*)x;
    const float4* h4 = (const float4*)h;
    float acc = 0.f;
#pragma unroll
    for (int k = 0; k < H / 256; ++k) {
        int j = k * 64 + lane;
        float4 wv = Wi4[j]; float4 v = x4[j];
        acc += wv.x * v.x + wv.y * v.y + wv.z * v.z + wv.w * v.w;
    }
#pragma unroll
    for (int k = 0; k < H / 256; ++k) {
        int j = k * 64 + lane;
        float4 wv = Wh4[j]; float4 v = h4[j];
        acc += wv.x * v.x + wv.y * v.y + wv.z * v.z + wv.w * v.w;
    }
    for (int off = 32; off > 0; off >>= 1) acc += __shfl_down(acc, off, 64);
    if (lane == 0) gates[row] = acc + bih[row] + bhh[row];
}
__global__ __launch_bounds__(256) void update_kernel(
    const float* __restrict__ gates,
    float* __restrict__ xv, float* __restrict__ hv, float* __restrict__ cv,
    const float* __restrict__ dec, int nclass,
    const float* __restrict__ enc, int* __restrict__ idx_ptr) {
    const int t = threadIdx.x;
    __shared__ float red[256];
    __shared__ float logits[16];
    __shared__ int sidx;
    float hl[8];
#pragma unroll
    for (int k = 0; k < 8; ++k) {
        int j = k * 256 + t;
        float si = sigm(gates[j]);
        float sf = sigm(gates[H + j]);
        float so = sigm(gates[3 * H + j]);
        float tg = tanhf(gates[2 * H + j]);
        float c2 = sf * cv[j] + si * tg;
        float h2 = so * tanhf(c2);
        cv[j] = c2; hv[j] = h2; hl[k] = h2;
    }
    __syncthreads();
    for (int cl = 0; cl < nclass; ++cl) {
        const float* dr = dec + (size_t)cl * H;
        float p = 0.f;
#pragma unroll
        for (int k = 0; k < 8; ++k) p += hl[k] * dr[k * 256 + t];
        red[t] = p;
        __syncthreads();
        for (int s = 128; s > 0; s >>= 1) {
            if (t < s) red[t] += red[t + s];
            __syncthreads();
        }
        if (t == 0) logits[cl] = red[0];
        __syncthreads();
    }
    if (t == 0) {
        float best = logits[0]; int bi = 0;
        for (int cl = 1; cl < nclass; ++cl)
            if (logits[cl] > best) { best = logits[cl]; bi = cl; }
        sidx = bi; *idx_ptr = bi;
    }
    __syncthreads();
    if (enc != nullptr) {
        const float* er = enc + (size_t)sidx * H;
#pragma unroll
        for (int k = 0; k < 8; ++k) xv[k * 256 + t] = er[k * 256 + t];
    }
}
__global__ __launch_bounds__(256) void final_kernel(
    const float* __restrict__ hv, const float* __restrict__ cv,
    const int* __restrict__ idx_ptr, float* __restrict__ out) {
    const int tid = blockIdx.x * 256 + threadIdx.x;
    const int col = tid & (H / 4 - 1);
    ((float4*)(out + B))[tid] = ((const float4*)hv)[col];
    ((float4*)(out + B + (size_t)B * H))[tid] = ((const float4*)cv)[col];
    if (tid < B) out[tid] = (float)(*idx_ptr);
}

extern "C" void kernel_launch(void* const* d_in, const int* in_sizes, int n_in,
                              void* d_out, int out_size, void* d_ws, size_t ws_size,
                              hipStream_t stream) {
    const float* W_ih      = (const float*)d_in[1];
    const float* W_hh      = (const float*)d_in[2];
    const float* b_ih      = (const float*)d_in[3];
    const float* b_hh      = (const float*)d_in[4];
    const float* enc_act   = (const float*)d_in[5];
    const float* enc_block = (const float*)d_in[6];
    const float* dec_act   = (const float*)d_in[7];
    const float* dec_block = (const float*)d_in[8];
    float* out = (float*)d_out;
    char* ws = (char*)d_ws;

    if (ws_size >= WS_NEED) {
        uint32_t* Ex = (uint32_t*)(ws + OFF_E);
        uint32_t* Wx = (uint32_t*)(ws + OFF_WX);
        unsigned long long* hb0 = (unsigned long long*)(ws + OFF_H0);
        unsigned long long* hb1 = (unsigned long long*)(ws + OFF_H1);
        unsigned long long* cbf = (unsigned long long*)(ws + OFF_CB);

        build_e_kernel<<<NEMB + 1, 256, 0, stream>>>(
            enc_act, enc_block, Ex, (uint4*)(ws + OFF_H0));
        wx_kernel<<<512, 256, 0, stream>>>(W_ih, Wx);
        lstm_persist<<<NBLK, NTHR, 0, stream>>>(
            (const uint16_t*)Wx, W_hh, b_ih, b_hh, (const uint16_t*)Ex,
            dec_act, dec_block, hb0, hb1, cbf, out);
        return;
    }

    // fallback: fp32 multi-kernel path
    float* state = (float*)d_ws;
    float* xv = state;
    float* hv = state + H;
    float* cv = state + 2 * H;
    float* gates = state + 3 * H;
    int* idxp = (int*)(state + 7 * H);

    zero_c_kernel<<<8, 256, 0, stream>>>(cv);
    bias_gates_kernel<<<32, 256, 0, stream>>>(b_ih, b_hh, gates);
    update_kernel<<<1, 256, 0, stream>>>(gates, xv, hv, cv, dec_act, 4,
                                         enc_act, idxp);
    for (int bid = 1; bid < NB; ++bid) {
        gates_kernel<<<2048, 256, 0, stream>>>(W_ih, W_hh, b_ih, b_hh,
                                               xv, hv, gates);
        update_kernel<<<1, 256, 0, stream>>>(
            gates, xv, hv, cv,
            dec_block + (size_t)(bid - 1) * (NB - 1) * H, bid,
            enc_block + (size_t)(bid - 1) * (NB - 1) * H, idxp);
        gates_kernel<<<2048, 256, 0, stream>>>(W_ih, W_hh, b_ih, b_hh,
                                               xv, hv, gates);
        update_kernel<<<1, 256, 0, stream>>>(
            gates, xv, hv, cv,
            dec_act + (size_t)bid * 4 * H, 4,
            (bid < NB - 1) ? (enc_act + (size_t)bid * 4 * H) : nullptr, idxp);
    }
    final_kernel<<<2048, 256, 0, stream>>>(hv, cv, idxp, out);
}